// Round 10
// baseline (299.681 us; speedup 1.0000x reference)
//
#include <hip/hip_runtime.h>

#define NNODES 50000
#define NEDGES 800000
#define CHUNK 3125          // edges per CSR block (256 blocks * 3125 = 800000)

typedef __attribute__((ext_vector_type(8))) short short8;
typedef __attribute__((ext_vector_type(4))) float floatx4;
typedef __attribute__((ext_vector_type(8))) _Float16 f16x8;

// async global->LDS, 16B per lane (global_load_lds_dwordx4).
// LDS dest MUST be wave-uniform base + lane*16.
__device__ __forceinline__ void async16(const void* g, void* l) {
    __builtin_amdgcn_global_load_lds(
        (const __attribute__((address_space(1))) unsigned int*)g,
        (__attribute__((address_space(3))) unsigned int*)l, 16, 0, 0);
}

__device__ __forceinline__ void split_bf16(float v, short& hi, short& lo) {
    unsigned u = __float_as_uint(v);
    unsigned hu = u & 0xffff0000u;
    hi = (short)(hu >> 16);
    float r = v - __uint_as_float(hu);
    lo = (short)(__float_as_uint(r) >> 16);
}

// ------ prep: weight transpose/split + coarse histogram ------------------

#define PREP_WBLK 224
#define PREP_TOT  (PREP_WBLK + 256)

__global__ __launch_bounds__(256) void k_prep(
    const float* __restrict__ W0, short* __restrict__ W0h, short* __restrict__ W0l,
    const float* __restrict__ W1, short* __restrict__ W1h, short* __restrict__ W1l,
    const float* __restrict__ W2, short* __restrict__ W2h, short* __restrict__ W2l,
    const int* __restrict__ dst, int* __restrict__ hist2d) {
    int b = blockIdx.x, t = threadIdx.x;
    if (b < PREP_WBLK) {
        int id = b * 256 + t;
        const float* W; short *Wh, *Wl; int K, F;
        if (id < 32768) { W = W0; Wh = W0h; Wl = W0l; K = 256; F = 128; }
        else if (id < 49152) { id -= 32768; W = W1; Wh = W1h; Wl = W1l; K = 128; F = 128; }
        else if (id < 57344) { id -= 49152; W = W2; Wh = W2h; Wl = W2l; K = 128; F = 64; }
        else return;
        int f = id / K, k = id - f * K;
        short h, l;
        split_bf16(W[(size_t)k * F + f], h, l);
        Wh[id] = h;
        Wl[id] = l;
    } else {
        // per-block coarse histogram of dst>>8 (no global atomics)
        __shared__ int h[256];
        int bb = b - PREP_WBLK;
        h[t] = 0;
        __syncthreads();
        int e0 = bb * CHUNK;
#pragma unroll
        for (int k = 0; k < 13; k++) {
            int o = k * 256 + t;
            if (o < CHUNK) atomicAdd(&h[dst[e0 + o] >> 8], 1);
        }
        __syncthreads();
        hist2d[bb * 256 + t] = h[t];
    }
}

// P2 (self-scanning): deterministic coarse scatter, LDS cursors only.
__global__ __launch_bounds__(256) void k_p2(const int* __restrict__ src,
                                            const int* __restrict__ dst,
                                            const int* __restrict__ hist2d,
                                            unsigned* __restrict__ buck) {
    __shared__ int ex[256], cur[256];
    int t = threadIdx.x, b = blockIdx.x;
    int tot = 0, pre = 0;
    for (int bb = 0; bb < 256; bb++) {
        int v = hist2d[bb * 256 + t];
        tot += v;
        pre += (bb < b) ? v : 0;
    }
    ex[t] = tot;
    __syncthreads();
    for (int o = 1; o < 256; o <<= 1) {
        int xx = (t >= o) ? ex[t - o] : 0;
        __syncthreads();
        ex[t] += xx;
        __syncthreads();
    }
    cur[t] = (ex[t] - tot) + pre;
    __syncthreads();
    int e0 = b * CHUNK;
#pragma unroll
    for (int k = 0; k < 13; k++) {
        int o = k * 256 + t;
        if (o < CHUNK) {
            int s = src[e0 + o], d = dst[e0 + o];
            int p = atomicAdd(&cur[d >> 8], 1);   // LDS atomic only
            buck[p] = (unsigned)s | ((unsigned)(d & 255) << 16);
        }
    }
}

// P3 (self-scanning): finalize coarse bin b -> rowptr/dinv/ssrc.
__global__ __launch_bounds__(256) void k_p3(const unsigned* __restrict__ buck,
                                            const int* __restrict__ hist2d,
                                            int* __restrict__ rowptr,
                                            float* __restrict__ dinv,
                                            int* __restrict__ ssrc) {
    __shared__ int ex[256], cur[256], h[256], sS0[1], sS[1];
    int t = threadIdx.x, b = blockIdx.x;
    int tot = 0;
    for (int bb = 0; bb < 256; bb++) tot += hist2d[bb * 256 + t];
    ex[t] = tot;
    __syncthreads();
    for (int o = 1; o < 256; o <<= 1) {
        int xx = (t >= o) ? ex[t - o] : 0;
        __syncthreads();
        ex[t] += xx;
        __syncthreads();
    }
    if (t == b) { sS0[0] = ex[t] - tot; sS[0] = tot; }
    h[t] = 0;
    __syncthreads();
    int s0 = sS0[0], S = sS[0];
    for (int i = t; i < S; i += 256)
        atomicAdd(&h[(buck[s0 + i] >> 16) & 255], 1);
    __syncthreads();
    int v = h[t];
    ex[t] = v;
    __syncthreads();
    for (int o = 1; o < 256; o <<= 1) {
        int xx = (t >= o) ? ex[t - o] : 0;
        __syncthreads();
        ex[t] += xx;
        __syncthreads();
    }
    int excl = ex[t] - v;
    int n = b * 256 + t;
    if (n < NNODES) {
        rowptr[n] = s0 + excl;
        dinv[n] = rsqrtf((float)v + 1.0f);
    }
    if (b == 0 && t == 0) rowptr[NNODES] = NEDGES;
    cur[t] = excl;
    __syncthreads();
    for (int i = t; i < S; i += 256) {
        unsigned pk = buck[s0 + i];
        int dl = (pk >> 16) & 255;
        int p = atomicAdd(&cur[dl], 1);
        ssrc[s0 + p] = (int)(pk & 0xFFFFu);
    }
}

// ------ B staging helper: chunk-major layout, conflict-free reads --------
// Per BK=32 step q: slot l = c*BN + n (c=0..3 k-chunk, n=row). 16B/slot.
// MFMA read at (fq*BN + n): 16 lanes same fq -> consecutive slots -> free.

template <int BN, int K>
__device__ __forceinline__ void stage_b(const short* __restrict__ Bh,
                                        const short* __restrict__ Bl,
                                        short* sBh, short* sBl,
                                        int w, int lane, int q) {
    constexpr int JJN = BN / 64;        // j-groups per wave
#pragma unroll
    for (int jj = 0; jj < JJN; jj++) {
        int j = w * JJN + jj;
        int l = j * 64 + lane;
        int c = l / BN, n = l % BN;
        size_t go = (size_t)n * K + q * 32 + c * 8;
        async16(&Bh[go], &sBh[l * 8]);
        async16(&Bl[go], &sBl[l * 8]);
    }
}

// ------ gemm0: g16 = fp16((x @ W0) * dinv[row]) --------------------------
// Register-A: lane (fr,fq) owns row w*16+fr; per q loads its own 8 fp32,
// splits in-register. Only B goes through LDS (16 KB). BM=64, K=256.

__global__ __launch_bounds__(256) void k_gemm0(
    const float* __restrict__ x, const short* __restrict__ Bh,
    const short* __restrict__ Bl, const float* __restrict__ dinv,
    _Float16* __restrict__ g16) {
    __shared__ __align__(16) short sBh[512 * 8], sBl[512 * 8];
    const int t = threadIdx.x, lane = t & 63, w = t >> 6;
    const int row0 = blockIdx.x * 64;
    const int fr = lane & 15, fq = lane >> 4;
    int grow = row0 + w * 16 + fr;
    if (grow >= NNODES) grow = NNODES - 1;
    const float* xr = x + (size_t)grow * 256 + fq * 8;

    floatx4 acc[8] = {};
    stage_b<128, 256>(Bh, Bl, sBh, sBl, w, lane, 0);

    for (int q = 0; q < 8; q++) {
        // A fragment: 8 fp32 -> bf16 hi/lo in registers
        const float4* xp = (const float4*)(xr + q * 32);
        float4 f0 = xp[0], f1 = xp[1];
        float va[8] = {f0.x, f0.y, f0.z, f0.w, f1.x, f1.y, f1.z, f1.w};
        short8 ah, al;
#pragma unroll
        for (int j = 0; j < 8; j++) {
            short h, l;
            split_bf16(va[j], h, l);
            ah[j] = h; al[j] = l;
        }
        if (q > 0) stage_b<128, 256>(Bh, Bl, sBh, sBl, w, lane, q);
        __syncthreads();
#pragma unroll
        for (int nt = 0; nt < 8; nt++) {
            int sl = fq * 128 + nt * 16 + fr;
            short8 bh = *(const short8*)&sBh[sl * 8];
            short8 bl = *(const short8*)&sBl[sl * 8];
            acc[nt] = __builtin_amdgcn_mfma_f32_16x16x32_bf16(ah, bh, acc[nt], 0, 0, 0);
            acc[nt] = __builtin_amdgcn_mfma_f32_16x16x32_bf16(ah, bl, acc[nt], 0, 0, 0);
            acc[nt] = __builtin_amdgcn_mfma_f32_16x16x32_bf16(al, bh, acc[nt], 0, 0, 0);
        }
        __syncthreads();
    }
#pragma unroll
    for (int rr = 0; rr < 4; rr++) {
        int gw = row0 + w * 16 + fq * 4 + rr;
        if (gw < NNODES) {
            float dv = dinv[gw];
#pragma unroll
            for (int nt = 0; nt < 8; nt++)
                g16[(size_t)gw * 128 + nt * 16 + fr] =
                    (_Float16)(acc[nt][rr] * dv);
        }
    }
}

// ------ fused agg+gemm: gout = fp16((relu(agg(gin)+b) @ W) * dinv) -------
// Register-A gather: lane (fr,fq) gathers chunks q*4+fq (q=0..3) of row
// w*16+fr — exactly its 4 MFMA A-fragments. 4 indep 16B loads/edge,
// edge-unrolled x2 (8 in flight). No A-LDS; B 16 KB chunk-major.

template <int BN>
__global__ __launch_bounds__(256) void k_fg(
    const _Float16* __restrict__ gin, const int* __restrict__ ssrc,
    const int* __restrict__ rowptr, const float* __restrict__ dinv,
    const float* __restrict__ bias, const short* __restrict__ Bh,
    const short* __restrict__ Bl, _Float16* __restrict__ gout) {
    constexpr int NT = BN / 16;
    __shared__ __align__(16) short sBh[4 * BN * 8], sBl[4 * BN * 8];
    const int t = threadIdx.x, lane = t & 63, w = t >> 6;
    const int row0 = blockIdx.x * 64;
    const int fr = lane & 15, fq = lane >> 4;
    const f16x8* gp = (const f16x8*)gin;

    stage_b<BN, 128>(Bh, Bl, sBh, sBl, w, lane, 0);

    // ---- gather phase (registers only) ----
    int grow = row0 + w * 16 + fr;
    if (grow >= NNODES) grow = NNODES - 1;
    float acc[4][8];
#pragma unroll
    for (int q = 0; q < 4; q++) {
        f16x8 sv = gp[(size_t)grow * 16 + q * 4 + fq];
#pragma unroll
        for (int j = 0; j < 8; j++) acc[q][j] = (float)sv[j];
    }
    int e0 = rowptr[grow], e1 = rowptr[grow + 1];
    int e = e0;
    for (; e + 2 <= e1; e += 2) {
        int s0 = ssrc[e], s1 = ssrc[e + 1];
        f16x8 u[4], v[4];
#pragma unroll
        for (int q = 0; q < 4; q++) {
            u[q] = gp[(size_t)s0 * 16 + q * 4 + fq];
            v[q] = gp[(size_t)s1 * 16 + q * 4 + fq];
        }
#pragma unroll
        for (int q = 0; q < 4; q++)
#pragma unroll
            for (int j = 0; j < 8; j++)
                acc[q][j] += (float)u[q][j] + (float)v[q][j];
    }
    for (; e < e1; e++) {
        int s = ssrc[e];
#pragma unroll
        for (int q = 0; q < 4; q++) {
            f16x8 u = gp[(size_t)s * 16 + q * 4 + fq];
#pragma unroll
            for (int j = 0; j < 8; j++) acc[q][j] += (float)u[j];
        }
    }
    // epilogue of agg: dinv, bias, relu, split to A-fragments
    float dv = dinv[grow];
    short8 ah[4], al[4];
#pragma unroll
    for (int q = 0; q < 4; q++) {
#pragma unroll
        for (int j = 0; j < 8; j++) {
            float o = fmaxf(acc[q][j] * dv + bias[(q * 4 + fq) * 8 + j], 0.f);
            short hh, ll;
            split_bf16(o, hh, ll);
            ah[q][j] = hh; al[q][j] = ll;
        }
    }

    // ---- MFMA phase ----
    floatx4 accC[NT] = {};
    for (int q = 0; q < 4; q++) {
        if (q > 0) stage_b<BN, 128>(Bh, Bl, sBh, sBl, w, lane, q);
        __syncthreads();
#pragma unroll
        for (int nt = 0; nt < NT; nt++) {
            int sl = fq * BN + nt * 16 + fr;
            short8 bh = *(const short8*)&sBh[sl * 8];
            short8 bl = *(const short8*)&sBl[sl * 8];
            accC[nt] = __builtin_amdgcn_mfma_f32_16x16x32_bf16(ah[q], bh, accC[nt], 0, 0, 0);
            accC[nt] = __builtin_amdgcn_mfma_f32_16x16x32_bf16(ah[q], bl, accC[nt], 0, 0, 0);
            accC[nt] = __builtin_amdgcn_mfma_f32_16x16x32_bf16(al[q], bh, accC[nt], 0, 0, 0);
        }
        __syncthreads();
    }

#pragma unroll
    for (int rr = 0; rr < 4; rr++) {
        int gw = row0 + w * 16 + fq * 4 + rr;
        if (gw < NNODES) {
            float dv2 = dinv[gw];
#pragma unroll
            for (int nt = 0; nt < NT; nt++)
                gout[(size_t)gw * BN + nt * 16 + fr] =
                    (_Float16)(accC[nt][rr] * dv2);
        }
    }
}

// ------ final aggregation (thread-per-(node,16B-chunk), fp32 out) --------

template <int F>
__global__ __launch_bounds__(256) void k_agg(const _Float16* __restrict__ g,
                                             const int* __restrict__ ssrc,
                                             const int* __restrict__ rowptr,
                                             const float* __restrict__ dinv,
                                             const float* __restrict__ bias,
                                             float* __restrict__ outf) {
    constexpr int F8 = F / 8;
    int gid = blockIdx.x * 256 + threadIdx.x;
    int n = gid / F8;
    if (n >= NNODES) return;
    int c8 = gid - n * F8;
    const f16x8* gp = (const f16x8*)g;

    f16x8 sv = gp[(size_t)n * F8 + c8];
    float a0[8], a1[8], a2[8], a3[8];
#pragma unroll
    for (int j = 0; j < 8; j++) {
        a0[j] = (float)sv[j];
        a1[j] = 0.f; a2[j] = 0.f; a3[j] = 0.f;
    }
    int e0 = rowptr[n], e1 = rowptr[n + 1];
    int e = e0;
    for (; e + 4 <= e1; e += 4) {
        int s0 = ssrc[e], s1 = ssrc[e + 1], s2 = ssrc[e + 2], s3 = ssrc[e + 3];
        f16x8 v0 = gp[(size_t)s0 * F8 + c8];
        f16x8 v1 = gp[(size_t)s1 * F8 + c8];
        f16x8 v2 = gp[(size_t)s2 * F8 + c8];
        f16x8 v3 = gp[(size_t)s3 * F8 + c8];
#pragma unroll
        for (int j = 0; j < 8; j++) {
            a0[j] += (float)v0[j];
            a1[j] += (float)v1[j];
            a2[j] += (float)v2[j];
            a3[j] += (float)v3[j];
        }
    }
    for (; e < e1; e++) {
        int s = ssrc[e];
        f16x8 v = gp[(size_t)s * F8 + c8];
#pragma unroll
        for (int j = 0; j < 8; j++) a0[j] += (float)v[j];
    }
    float dv = dinv[n];
    float o[8];
#pragma unroll
    for (int j = 0; j < 8; j++) {
        float s = (a0[j] + a1[j]) + (a2[j] + a3[j]);
        o[j] = s * dv + bias[c8 * 8 + j];
    }
    *(float4*)&outf[(size_t)n * F + c8 * 8] = make_float4(o[0], o[1], o[2], o[3]);
    *(float4*)&outf[(size_t)n * F + c8 * 8 + 4] = make_float4(o[4], o[5], o[6], o[7]);
}

// ---------------- launch ----------------

static inline size_t align256(size_t x) { return (x + 255) & ~(size_t)255; }

extern "C" void kernel_launch(void* const* d_in, const int* in_sizes, int n_in,
                              void* d_out, int out_size, void* d_ws, size_t ws_size,
                              hipStream_t stream) {
    const float* x  = (const float*)d_in[0];
    const int*   ei = (const int*)d_in[1];
    const float* W0 = (const float*)d_in[2];
    const float* b0 = (const float*)d_in[3];
    const float* W1 = (const float*)d_in[4];
    const float* b1 = (const float*)d_in[5];
    const float* W2 = (const float*)d_in[6];
    const float* b2 = (const float*)d_in[7];
    float* out = (float*)d_out;

    const int* src = ei;
    const int* dst = ei + NEDGES;

    char* w = (char*)d_ws;
    size_t off = 0;
    float* dinv    = (float*)(w + off); off = align256(off + NNODES * 4);
    int* rowptr    = (int*)(w + off);   off = align256(off + (NNODES + 1) * 4);
    int* hist2d    = (int*)(w + off);   off = align256(off + 256 * 256 * 4);
    unsigned* buck = (unsigned*)(w + off); off = align256(off + (size_t)NEDGES * 4);
    int* ssrc      = (int*)(w + off);   off = align256(off + (size_t)NEDGES * 4);
    short* W0h     = (short*)(w + off); off = align256(off + 256 * 128 * 2);
    short* W0l     = (short*)(w + off); off = align256(off + 256 * 128 * 2);
    short* W1h     = (short*)(w + off); off = align256(off + 128 * 128 * 2);
    short* W1l     = (short*)(w + off); off = align256(off + 128 * 128 * 2);
    short* W2h     = (short*)(w + off); off = align256(off + 128 * 64 * 2);
    short* W2l     = (short*)(w + off); off = align256(off + 128 * 64 * 2);
    _Float16* g16a = (_Float16*)(w + off); off = align256(off + (size_t)NNODES * 128 * 2);
    _Float16* g16b = (_Float16*)(w + off); off = align256(off + (size_t)NNODES * 128 * 2);
    _Float16* g16c = (_Float16*)(w + off); off = align256(off + (size_t)NNODES * 64 * 2);

    const int MB = (NNODES + 63) / 64;           // 782
    const int AB64 = (NNODES * 8 + 255) / 256;   // 1563

    // 1) prep: weights + coarse histogram
    k_prep<<<PREP_TOT, 256, 0, stream>>>(W0, W0h, W0l, W1, W1h, W1l,
                                         W2, W2h, W2l, dst, hist2d);
    // 2) coarse scatter
    k_p2<<<256, 256, 0, stream>>>(src, dst, hist2d, buck);
    // 3) finalize: rowptr/dinv/ssrc
    k_p3<<<256, 256, 0, stream>>>(buck, hist2d, rowptr, dinv, ssrc);
    // 4) layer-0 gemm (direct x, register-A)
    k_gemm0<<<MB, 256, 0, stream>>>(x, W0h, W0l, dinv, g16a);
    // 5) fused agg0+gemm1
    k_fg<128><<<MB, 256, 0, stream>>>(g16a, ssrc, rowptr, dinv, b0, W1h, W1l, g16b);
    // 6) fused agg1+gemm2
    k_fg<64><<<MB, 256, 0, stream>>>(g16b, ssrc, rowptr, dinv, b1, W2h, W2l, g16c);
    // 7) final aggregation -> fp32 out
    k_agg<64><<<AB64, 256, 0, stream>>>(g16c, ssrc, rowptr, dinv, b2, out);
    (void)in_sizes; (void)n_in; (void)out_size; (void)ws_size;
}